// Round 6
// baseline (189.770 us; speedup 1.0000x reference)
//
#include <hip/hip_runtime.h>
#include <math.h>

// BioREDirect, 2-kernel version, barrier-free MFMA GEMM.
// K1 (1024 thr, 192 blocks): online-softmax ragged attention-pool -> Pbf (bf16,ws);
//     also bf16-converts dense W -> Wbf (ws) at the end (bulk-parallel), and
//     bias-inits out[] (b==0 blocks).
// K2 (256 thr, 36 blocks): dense+tanh via 16x16x32 bf16 MFMA with fragments
//     loaded DIRECTLY from global (bf16x8 = one dwordx4; A[m=lane&15][k=8q+j])
//     — no LDS staging, no barriers in the K-loop, zero VALU conversions.
//     Classifier partials atomicAdd'ed into out.
// NOTE: timed iteration carries ~150us of harness restore/poison fills (fixed).

#define Hdim 768
#define Kdim 64
#define Sdim 512
#define Bdim 64

typedef float f32x4 __attribute__((ext_vector_type(4)));
typedef short bf16x8 __attribute__((ext_vector_type(8)));

__device__ __forceinline__ unsigned short f2bf(float f) {
    union { float f; unsigned int u; } c; c.f = f;
    unsigned int u = c.u + 0x7FFFu + ((c.u >> 16) & 1u);  // RNE
    return (unsigned short)(u >> 16);
}

__device__ __forceinline__ void cvt8(const float* __restrict__ src,
                                     unsigned short* __restrict__ dst) {
    float4 x = *(const float4*)src, y = *(const float4*)(src + 4);
    *(ushort4*)dst       = make_ushort4(f2bf(x.x), f2bf(x.y), f2bf(x.z), f2bf(x.w));
    *(ushort4*)(dst + 4) = make_ushort4(f2bf(y.x), f2bf(y.y), f2bf(y.z), f2bf(y.w));
}

// ---------------- K1: online-softmax attention pooling (16 waves) ----------------
__global__ __launch_bounds__(1024) void k_pool(
    const float* __restrict__ seq,
    const int* __restrict__ idxr, const int* __restrict__ lenr,
    const int* __restrict__ idxn, const int* __restrict__ lenn,
    const int* __restrict__ idxd, const int* __restrict__ lend,
    const float* __restrict__ cbr, const float* __restrict__ cbn,
    const float* __restrict__ cbd,
    const float* __restrict__ dWr, const float* __restrict__ dWn,
    const float* __restrict__ dWd,
    unsigned short* __restrict__ Wbf,   // [3][768][768] bf16
    unsigned short* __restrict__ Pbf,   // [3][64][768]  bf16
    float* __restrict__ out)            // bias-init here; K2 atomicAdds partials
{
    const int b = blockIdx.x, g = blockIdx.y;
    const int tid = threadIdx.x, lane = tid & 63, wave = tid >> 6;  // 16 waves

    const int* idxp = (g == 0) ? idxr : (g == 1) ? idxn : idxd;
    const int* lnp  = (g == 0) ? lenr : (g == 1) ? lenn : lend;

    __shared__ int   sidx[Kdim];
    __shared__ float wm[16], wl[16], coef[16];
    __shared__ float wpart[16][Hdim];   // 48 KB

    if (tid < Kdim) sidx[tid] = idxp[b * Kdim + tid];
    const int len = lnp[b];

    // bias-init of out (stream-ordered before K2's atomics)
    if (b == 0) {
        if (g == 0)      { if (tid < 576) out[tid]       = cbr[tid % 9]; }
        else if (g == 1) { if (tid < 192) out[576 + tid] = cbn[tid % 3]; }
        else             { if (tid < 192) out[768 + tid] = cbd[tid % 3]; }
    }
    __syncthreads();

    unsigned short* Pb = Pbf + ((size_t)g * Bdim + b) * Hdim;

    if (len > 0) {
        const float* row0 = seq + ((size_t)b * Sdim + sidx[0]) * Hdim;
        float g0[12];
#pragma unroll
        for (int k = 0; k < 3; ++k) {
            float4 v = *(const float4*)(row0 + 4 * lane + 256 * k);
            g0[4 * k + 0] = v.x; g0[4 * k + 1] = v.y;
            g0[4 * k + 2] = v.z; g0[4 * k + 3] = v.w;
        }

        float m = -1e30f, l = 0.f;
        float p[12] = {0,0,0,0,0,0,0,0,0,0,0,0};

        for (int j = wave; j < len; j += 16) {
            const float* rowj = seq + ((size_t)b * Sdim + sidx[j]) * Hdim;
            float v[12];
#pragma unroll
            for (int k = 0; k < 3; ++k) {
                float4 t = *(const float4*)(rowj + 4 * lane + 256 * k);
                v[4 * k + 0] = t.x; v[4 * k + 1] = t.y;
                v[4 * k + 2] = t.z; v[4 * k + 3] = t.w;
            }
            float s = 0.f;
#pragma unroll
            for (int k = 0; k < 12; ++k) s += g0[k] * v[k];
#pragma unroll
            for (int off = 32; off > 0; off >>= 1) s += __shfl_xor(s, off, 64);

            float mn    = fmaxf(m, s);
            float scale = __expf(m - mn);
            float e     = __expf(s - mn);
            l = l * scale + e;
#pragma unroll
            for (int k = 0; k < 12; ++k) p[k] = p[k] * scale + e * v[k];
            m = mn;
        }

        if (lane == 0) { wm[wave] = m; wl[wave] = l; }
#pragma unroll
        for (int k = 0; k < 3; ++k)
            *(float4*)&wpart[wave][4 * lane + 256 * k] =
                make_float4(p[4 * k], p[4 * k + 1], p[4 * k + 2], p[4 * k + 3]);
        __syncthreads();

        if (wave == 0 && lane < 16) {
            float mw = wm[lane], lw = wl[lane];
            float M = mw;
#pragma unroll
            for (int off = 8; off > 0; off >>= 1) M = fmaxf(M, __shfl_xor(M, off, 64));
            float sc = __expf(mw - M);        // 0 for waves with no j
            float Ls = lw * sc;
#pragma unroll
            for (int off = 8; off > 0; off >>= 1) Ls += __shfl_xor(Ls, off, 64);
            coef[lane] = sc / Ls;
        }
        __syncthreads();

        if (tid < Hdim) {
            float acc = 0.f;
#pragma unroll
            for (int w = 0; w < 16; ++w) acc += wpart[w][tid] * coef[w];
            Pb[tid] = f2bf(acc);
        }
    } else {
        if (tid < Hdim) Pb[tid] = f2bf(seq[(size_t)b * Sdim * Hdim + tid]);
    }

    // ---- bulk W -> bf16 convert for K2 (off the pooling critical path) ----
    {
        const float* dW = (g == 0) ? dWr : (g == 1) ? dWn : dWd;
        unsigned short* Wb = Wbf + (size_t)g * Hdim * Hdim;
        for (int e = (b * 1024 + tid) * 8; e < Hdim * Hdim; e += 64 * 1024 * 8)
            cvt8(dW + e, Wb + e);
    }
}

// ---------------- K2: barrier-free MFMA dense+tanh + fused classifier ----------------
__global__ __launch_bounds__(256) void k_dense_cls(
    const unsigned short* __restrict__ Wbf,   // [3][768][768] bf16
    const unsigned short* __restrict__ Pbf,   // [3][64][768]  bf16
    const float* __restrict__ dbr, const float* __restrict__ dbn,
    const float* __restrict__ dbd,
    const float* __restrict__ cWr, const float* __restrict__ cWn,
    const float* __restrict__ cWd,
    float* __restrict__ out)
{
    const int mt = blockIdx.x, g = blockIdx.y;
    const float *db, *cW; int nlab, off;
    if (g == 0)      { db = dbr; cW = cWr; nlab = 9; off = 0;   }
    else if (g == 1) { db = dbn; cW = cWn; nlab = 3; off = 576; }
    else             { db = dbd; cW = cWd; nlab = 3; off = 768; }
    const int i0 = mt * 64;

    const int tid = threadIdx.x, lane = tid & 63, wv = tid >> 6;
    const int q = lane >> 4, col = lane & 15;

    // A frag: W row (i0 + wv*16 + m), m = lane&15, k = ks + 8q + j  (8 contiguous)
    const unsigned short* Ap = Wbf + ((size_t)g * Hdim + i0 + wv * 16 + col) * Hdim + 8 * q;
    // B frag: P row (n*16 + col), k = ks + 8q + j
    const unsigned short* Bp = Pbf + ((size_t)g * Bdim + col) * Hdim + 8 * q;

    f32x4 acc[4] = {{0,0,0,0},{0,0,0,0},{0,0,0,0},{0,0,0,0}};

#pragma unroll 6
    for (int ks = 0; ks < Hdim; ks += 32) {
        bf16x8 a = *(const bf16x8*)(Ap + ks);
#pragma unroll
        for (int n = 0; n < 4; ++n) {
            bf16x8 bb = *(const bf16x8*)(Bp + (size_t)n * 16 * Hdim + ks);
            acc[n] = __builtin_amdgcn_mfma_f32_16x16x32_bf16(a, bb, acc[n], 0, 0, 0);
        }
    }

    // epilogue: tanh+bias -> LDS h-tile [i_local][b]
    __shared__ float hs[64][65];
#pragma unroll
    for (int n = 0; n < 4; ++n) {
        int bb = n * 16 + col;
#pragma unroll
        for (int r = 0; r < 4; ++r) {
            int il = wv * 16 + q * 4 + r;
            hs[il][bb] = tanhf(acc[n][r] + db[i0 + il]);
        }
    }
    __syncthreads();

    // classifier partial for this i-tile: out[b][c] += sum_il cW[c][i0+il]*h[il][b]
    for (int c = wv; c < nlab; c += 4) {
        const float* wr = cW + (size_t)c * Hdim + i0;
        float a = 0.f;
#pragma unroll 16
        for (int il = 0; il < 64; ++il)
            a += wr[il] * hs[il][lane];
        atomicAdd(&out[off + lane * nlab + c], a);
    }
}

extern "C" void kernel_launch(void* const* d_in, const int* in_sizes, int n_in,
                              void* d_out, int out_size, void* d_ws, size_t ws_size,
                              hipStream_t stream) {
    const float* seq  = (const float*)d_in[0];
    const int*   idxr = (const int*)d_in[1];
    const int*   lenr = (const int*)d_in[2];
    const int*   idxn = (const int*)d_in[3];
    const int*   lenn = (const int*)d_in[4];
    const int*   idxd = (const int*)d_in[5];
    const int*   lend = (const int*)d_in[6];
    const float* dWr  = (const float*)d_in[7];
    const float* dbr  = (const float*)d_in[8];
    const float* cWr  = (const float*)d_in[9];
    const float* cbr  = (const float*)d_in[10];
    const float* dWn  = (const float*)d_in[11];
    const float* dbn  = (const float*)d_in[12];
    const float* cWn  = (const float*)d_in[13];
    const float* cbn  = (const float*)d_in[14];
    const float* dWd  = (const float*)d_in[15];
    const float* dbd  = (const float*)d_in[16];
    const float* cWd  = (const float*)d_in[17];
    const float* cbd  = (const float*)d_in[18];
    float* out = (float*)d_out;

    unsigned short* Wbf = (unsigned short*)d_ws;            // 3*768*768 bf16 = 3,538,944 B
    unsigned short* Pbf = Wbf + (size_t)3 * Hdim * Hdim;    // 3*64*768  bf16 =   294,912 B

    k_pool<<<dim3(Bdim, 3), 1024, 0, stream>>>(
        seq, idxr, lenr, idxn, lenn, idxd, lend,
        cbr, cbn, cbd, dWr, dWn, dWd, Wbf, Pbf, out);
    k_dense_cls<<<dim3(Hdim / 64, 3), 256, 0, stream>>>(
        Wbf, Pbf, dbr, dbn, dbd, cWr, cWn, cWd, out);
}